// Round 1
// baseline (421.570 us; speedup 1.0000x reference)
//
#include <hip/hip_runtime.h>
#include <math.h>

// Capsule routing layer, fully fused: grouped 1x1 conv is rank-8 per group,
// so pred[i,j,d] = sum_k W[r,k]*x[ns*8+k,p] + bias[r]  (r = ns*160+j*16+d)
// is never materialized. Routing einsums factor through:
//   t[j,ns,k] = sum_p c[j,i]*x[k,p]   ->  s[j,d] = sum_{ns,k} W*t + sum_ns bias*cs
//   u[j,ns,k] = sum_d v[j,d]*W[r,k]   ->  delta_b[j,i] = sum_k u*x + ub
// One block per batch element; all state in LDS/registers.

#define BSZ   512
#define C_IN  256
#define HW    36          // 6*6 spatial
#define NS    32          // groups
#define NOC   10          // out caps
#define OD    16          // out dim
#define ROUTE 3
#define NIC   (NS*HW)     // 1152 in caps
#define NT    320         // threads per block (5 waves) = NOC*NS
#define BSTR  1160        // padded row stride for b logits (1160%32==8 -> spreads banks)

__global__ __launch_bounds__(NT, 2) void caps_kernel(
    const float* __restrict__ x,    // [BSZ, 256, 36]
    const float* __restrict__ Wc,   // [5120, 8]
    const float* __restrict__ bc,   // [5120]
    float* __restrict__ out)        // [BSZ, 10, 16]
{
    __shared__ float b_lds[NOC * BSTR];   // routing logits b[j][i]
    __shared__ float stat[NIC];           // per-in-cap: max_j + log(sum_j exp)
    __shared__ float tc[NOC * NS * 9];    // t[j][ns][k] (k<8) + cs at k=8; reused as u/ub
    __shared__ float s_lds[NOC * OD];     // s[j][d]
    __shared__ float fac[NOC];            // squash factor n/(1+n^2)

    const int tid  = threadIdx.x;
    const int bidx = blockIdx.x;
    const float* xb = x + (size_t)bidx * (C_IN * HW);

    // Register-cache x for the b-update phase: thread owns in-caps i = tid + 320*m
    float xr[4][8];
    #pragma unroll
    for (int m = 0; m < 4; ++m) {
        int i = tid + NT * m;
        if (i < NIC) {
            int ns = i / HW, p = i % HW;
            const float* xg = xb + ns * (8 * HW) + p;
            #pragma unroll
            for (int k = 0; k < 8; ++k) xr[m][k] = xg[k * HW];
        }
    }

    const int j_b  = tid % NOC;   // (j, ns) mapping for phases B and D1
    const int ns_b = tid / NOC;
    const float* xg_b = xb + ns_b * (8 * HW);

    for (int it = 0; it < ROUTE; ++it) {
        // ---- Phase A: softmax stats over j, per in-cap (skip iter 0: b==0) ----
        if (it > 0) {
            #pragma unroll
            for (int m = 0; m < 4; ++m) {
                int i = tid + NT * m;
                if (i < NIC) {
                    float bv[NOC];
                    float mx = -1e30f;
                    #pragma unroll
                    for (int j = 0; j < NOC; ++j) {
                        bv[j] = b_lds[j * BSTR + i];
                        mx = fmaxf(mx, bv[j]);
                    }
                    float se = 0.f;
                    #pragma unroll
                    for (int j = 0; j < NOC; ++j) se += __expf(bv[j] - mx);
                    stat[i] = mx + __logf(se);
                }
            }
            __syncthreads();
        }

        // ---- Phase B: t[j][ns][k] = sum_p c[j,i]*x[k,p], cs = sum_p c ----
        {
            float cp[HW];
            float cs;
            if (it == 0) {
                #pragma unroll
                for (int p = 0; p < HW; ++p) cp[p] = 0.1f;   // softmax of zeros
                cs = 3.6f;
            } else {
                cs = 0.f;
                const int ibase = ns_b * HW;
                #pragma unroll
                for (int p = 0; p < HW; ++p) {
                    float cv = __expf(b_lds[j_b * BSTR + ibase + p] - stat[ibase + p]);
                    cp[p] = cv;
                    cs += cv;
                }
            }
            float acc[8];
            #pragma unroll
            for (int k = 0; k < 8; ++k) acc[k] = 0.f;
            #pragma unroll
            for (int k = 0; k < 8; ++k) {
                const float4* xrow = (const float4*)(xg_b + k * HW);  // 36 floats, 16B-aligned
                #pragma unroll
                for (int q = 0; q < 9; ++q) {
                    float4 xv = xrow[q];
                    acc[k] += cp[4*q]*xv.x + cp[4*q+1]*xv.y + cp[4*q+2]*xv.z + cp[4*q+3]*xv.w;
                }
            }
            float* tptr = &tc[(j_b * NS + ns_b) * 9];
            #pragma unroll
            for (int k = 0; k < 8; ++k) tptr[k] = acc[k];
            tptr[8] = cs;
        }
        __syncthreads();

        // ---- Phase C: s[j][d] = sum_ns (W-row . t[j][ns]) + bias*cs ----
        if (tid < NOC * OD) {
            const int j = tid >> 4, d = tid & 15;
            float s = 0.f;
            for (int ns = 0; ns < NS; ++ns) {
                int r = ns * 160 + j * 16 + d;
                float4 w0 = *(const float4*)(Wc + (size_t)r * 8);
                float4 w1 = *(const float4*)(Wc + (size_t)r * 8 + 4);
                const float* tptr = &tc[(j * NS + ns) * 9];
                s += w0.x*tptr[0] + w0.y*tptr[1] + w0.z*tptr[2] + w0.w*tptr[3]
                   + w1.x*tptr[4] + w1.y*tptr[5] + w1.z*tptr[6] + w1.w*tptr[7]
                   + bc[r]*tptr[8];
            }
            s_lds[tid] = s;
        }
        __syncthreads();

        // ---- squash factor per j: fac = n/(1+n^2), n = ||s|| ----
        if (tid < NOC) {
            float ss = 0.f;
            #pragma unroll
            for (int d = 0; d < OD; ++d) { float sv = s_lds[tid * OD + d]; ss += sv * sv; }
            fac[tid] = sqrtf(ss) / (1.f + ss);
        }
        __syncthreads();

        if (it == ROUTE - 1) {
            // output v = s * fac
            if (tid < NOC * OD) {
                out[(size_t)bidx * (NOC * OD) + tid] = s_lds[tid] * fac[tid >> 4];
            }
            break;
        }

        // ---- Phase D1: u[j][ns][k] = sum_d v[j,d]*W[r,k], ub = sum_d v*bias ----
        // (tc safe to overwrite: phase-C reads completed before the post-C barrier)
        {
            const float fj = fac[j_b];
            float u[8] = {0.f,0.f,0.f,0.f,0.f,0.f,0.f,0.f};
            float ub = 0.f;
            #pragma unroll
            for (int d = 0; d < OD; ++d) {
                float vv = s_lds[j_b * OD + d] * fj;
                int r = ns_b * 160 + j_b * 16 + d;
                float4 w0 = *(const float4*)(Wc + (size_t)r * 8);
                float4 w1 = *(const float4*)(Wc + (size_t)r * 8 + 4);
                u[0] += vv * w0.x; u[1] += vv * w0.y; u[2] += vv * w0.z; u[3] += vv * w0.w;
                u[4] += vv * w1.x; u[5] += vv * w1.y; u[6] += vv * w1.z; u[7] += vv * w1.w;
                ub += vv * bc[r];
            }
            float* tptr = &tc[(j_b * NS + ns_b) * 9];
            #pragma unroll
            for (int k = 0; k < 8; ++k) tptr[k] = u[k];
            tptr[8] = ub;
        }
        __syncthreads();

        // ---- Phase D2: b[j][i] += sum_k u[j][ns][k]*x[k,p] + ub ----
        #pragma unroll
        for (int m = 0; m < 4; ++m) {
            int i = tid + NT * m;
            if (i < NIC) {
                int ns = i / HW;
                #pragma unroll
                for (int j = 0; j < NOC; ++j) {
                    const float* uptr = &tc[(j * NS + ns) * 9];
                    float dsum = uptr[8];
                    #pragma unroll
                    for (int k = 0; k < 8; ++k) dsum += uptr[k] * xr[m][k];
                    float prev = (it == 0) ? 0.f : b_lds[j * BSTR + i];
                    b_lds[j * BSTR + i] = prev + dsum;
                }
            }
        }
        __syncthreads();
    }
}

extern "C" void kernel_launch(void* const* d_in, const int* in_sizes, int n_in,
                              void* d_out, int out_size, void* d_ws, size_t ws_size,
                              hipStream_t stream) {
    const float* x  = (const float*)d_in[0];
    // d_in[1] = target (int32) — unused in forward
    const float* Wc = (const float*)d_in[2];
    const float* bc = (const float*)d_in[3];
    float* out = (float*)d_out;

    caps_kernel<<<dim3(BSZ), dim3(NT), 0, stream>>>(x, Wc, bc, out);
}

// Round 2
// 139.201 us; speedup vs baseline: 3.0285x; 3.0285x over previous
//
#include <hip/hip_runtime.h>
#include <math.h>

// Capsule routing, fully fused, zero-spill formulation.
// pred is rank-8 per group: pred[i,j,d] = W[r,:]·x[ns*8+:,p] + bias[r].
// Routing logits b are themselves rank-9 in x:
//   b[j,i] = Uacc[j,ns,:]·(x[ns*8+:,p], 1)
// where Uacc accumulates per-iteration u[j,ns,k] = sum_d v[j,d]*W[r,k]
// (and ub = sum_d v[j,d]*bias[r] in slot 8). So neither pred nor b is ever
// materialized. All per-thread state fits in <32 VGPR-resident scalars.

#define BSZ   512
#define C_IN  256
#define HW    36
#define NS    32
#define NOC   10
#define OD    16
#define ROUTE 3
#define NIC   (NS*HW)    // 1152
#define NT    320        // 5 waves = NOC*NS threads

__global__ __launch_bounds__(NT, 2) void caps_kernel(
    const float* __restrict__ x,    // [BSZ, 256, 36]
    const float* __restrict__ Wc,   // [5120, 8]
    const float* __restrict__ bc,   // [5120]
    float* __restrict__ out)        // [BSZ, 10, 16]
{
    __shared__ float xs[8 * NIC];       // 36864 B: xs[k][i], i=(ns,p); stride-1 in i
    __shared__ float stat[NIC];         //  4608 B: per-in-cap logsumexp over j
    __shared__ float Uacc[NOC*NS*9];    // 11520 B: cumulative routing coefficients
    __shared__ float tc[NOC*NS*9];      // 11520 B: per-iter t[j][ns][k], cs at k=8
    __shared__ float s_lds[NOC*OD];     //   640 B
    __shared__ float fac[NOC];          //    40 B
    // total 65192 B <= 64 KiB -> 2 blocks/CU (512 blocks on 256 CUs)

    const int tid = threadIdx.x;
    const float* xb = x + (size_t)blockIdx.x * (C_IN * HW);

    // ---- Stage x transposed into LDS: xs[c&7][(c>>3)*HW + p] = x[c][p] ----
    for (int e4 = tid; e4 < (C_IN * HW) / 4; e4 += NT) {
        float4 v = ((const float4*)xb)[e4];
        int e = e4 * 4;
        float vv[4] = {v.x, v.y, v.z, v.w};
        #pragma unroll
        for (int q = 0; q < 4; ++q) {
            int c = (e + q) / HW, p = (e + q) % HW;
            xs[(c & 7) * NIC + (c >> 3) * HW + p] = vv[q];
        }
    }
    __syncthreads();

    const int j_b  = tid % NOC;   // (j, ns) ownership for phases B and D1
    const int ns_b = tid / NOC;

    for (int it = 0; it < ROUTE; ++it) {
        // ---- Phase A: stat[i] = logsumexp_j b[j,i], b computed from Uacc ----
        if (it > 0) {
            #pragma unroll
            for (int m = 0; m < 4; ++m) {
                int i = tid + NT * m;
                if (i < NIC) {
                    int ns = i / HW;
                    float xv[8];
                    #pragma unroll
                    for (int k = 0; k < 8; ++k) xv[k] = xs[k * NIC + i];
                    float bv[NOC];
                    float mx = -1e30f;
                    #pragma unroll
                    for (int j = 0; j < NOC; ++j) {
                        const float* ua = &Uacc[(j * NS + ns) * 9];
                        float bb = ua[8];
                        #pragma unroll
                        for (int k = 0; k < 8; ++k) bb += ua[k] * xv[k];
                        bv[j] = bb;
                        mx = fmaxf(mx, bb);
                    }
                    float se = 0.f;
                    #pragma unroll
                    for (int j = 0; j < NOC; ++j) se += __expf(bv[j] - mx);
                    stat[i] = mx + __logf(se);
                }
            }
            __syncthreads();
        }

        // ---- Phase B: t[j][ns][k] = sum_p c*x[k,p], cs in slot 8 ----
        {
            float ua[9];
            if (it > 0) {
                #pragma unroll
                for (int kk = 0; kk < 9; ++kk) ua[kk] = Uacc[(j_b * NS + ns_b) * 9 + kk];
            }
            float acc[9];
            #pragma unroll
            for (int kk = 0; kk < 9; ++kk) acc[kk] = 0.f;
            const int ibase = ns_b * HW;
            for (int p = 0; p < HW; ++p) {
                float xv[8];
                #pragma unroll
                for (int k = 0; k < 8; ++k) xv[k] = xs[k * NIC + ibase + p];
                float c;
                if (it == 0) {
                    c = 0.1f;                       // softmax of zeros
                } else {
                    float bb = ua[8];
                    #pragma unroll
                    for (int k = 0; k < 8; ++k) bb += ua[k] * xv[k];
                    c = __expf(bb - stat[ibase + p]);
                }
                acc[8] += c;
                #pragma unroll
                for (int k = 0; k < 8; ++k) acc[k] += c * xv[k];
            }
            float* tptr = &tc[(j_b * NS + ns_b) * 9];
            #pragma unroll
            for (int kk = 0; kk < 9; ++kk) tptr[kk] = acc[kk];
        }
        __syncthreads();

        // ---- Phase C: s[j][d] = sum_ns (W[r,:]·t[j][ns]) + bias[r]*cs ----
        if (tid < NOC * OD) {
            const int j = tid >> 4, d = tid & 15;
            float s = 0.f;
            for (int ns = 0; ns < NS; ++ns) {
                int r = ns * 160 + j * 16 + d;
                float4 w0 = *(const float4*)(Wc + (size_t)r * 8);
                float4 w1 = *(const float4*)(Wc + (size_t)r * 8 + 4);
                const float* tptr = &tc[(j * NS + ns) * 9];
                s += w0.x*tptr[0] + w0.y*tptr[1] + w0.z*tptr[2] + w0.w*tptr[3]
                   + w1.x*tptr[4] + w1.y*tptr[5] + w1.z*tptr[6] + w1.w*tptr[7]
                   + bc[r]*tptr[8];
            }
            s_lds[tid] = s;
        }
        __syncthreads();

        // ---- squash factor: fac[j] = n/(1+n^2) ----
        if (tid < NOC) {
            float ss = 0.f;
            #pragma unroll
            for (int d = 0; d < OD; ++d) { float sv = s_lds[tid * OD + d]; ss += sv * sv; }
            fac[tid] = sqrtf(ss) / (1.f + ss);
        }
        __syncthreads();

        if (it == ROUTE - 1) {
            if (tid < NOC * OD)
                out[(size_t)blockIdx.x * (NOC * OD) + tid] = s_lds[tid] * fac[tid >> 4];
            break;
        }

        // ---- Phase D1: u[j][ns][k] = sum_d v[j,d]*W[r,k]; Uacc += u ----
        {
            const float fj = fac[j_b];
            float u[9];
            #pragma unroll
            for (int kk = 0; kk < 9; ++kk) u[kk] = 0.f;
            #pragma unroll
            for (int d = 0; d < OD; ++d) {
                float vv = s_lds[j_b * OD + d] * fj;
                int r = ns_b * 160 + j_b * 16 + d;
                float4 w0 = *(const float4*)(Wc + (size_t)r * 8);
                float4 w1 = *(const float4*)(Wc + (size_t)r * 8 + 4);
                u[0] += vv * w0.x; u[1] += vv * w0.y; u[2] += vv * w0.z; u[3] += vv * w0.w;
                u[4] += vv * w1.x; u[5] += vv * w1.y; u[6] += vv * w1.z; u[7] += vv * w1.w;
                u[8] += vv * bc[r];
            }
            float* uptr = &Uacc[(j_b * NS + ns_b) * 9];
            if (it == 0) {
                #pragma unroll
                for (int kk = 0; kk < 9; ++kk) uptr[kk] = u[kk];
            } else {
                #pragma unroll
                for (int kk = 0; kk < 9; ++kk) uptr[kk] += u[kk];
            }
        }
        __syncthreads();
    }
}

extern "C" void kernel_launch(void* const* d_in, const int* in_sizes, int n_in,
                              void* d_out, int out_size, void* d_ws, size_t ws_size,
                              hipStream_t stream) {
    const float* x  = (const float*)d_in[0];
    // d_in[1] = target (int32) — unused in forward
    const float* Wc = (const float*)d_in[2];
    const float* bc = (const float*)d_in[3];
    float* out = (float*)d_out;

    caps_kernel<<<dim3(BSZ), dim3(NT), 0, stream>>>(x, Wc, bc, out);
}